// Round 1
// baseline (714.500 us; speedup 1.0000x reference)
//
#include <hip/hip_runtime.h>

#define BS_T   16384
#define XDIM   4096
#define KDIM   512
#define NKEYS  4096
#define KTOP   16

typedef _Float16 half8  __attribute__((ext_vector_type(8)));
typedef _Float16 half4  __attribute__((ext_vector_type(4)));
typedef float    floatx4 __attribute__((ext_vector_type(4)));

// ---------------- fp32 -> fp16 convert ----------------
__global__ __launch_bounds__(256) void cvt_f32_f16(const float* __restrict__ in,
                                                   _Float16* __restrict__ out, int n4) {
  int i = blockIdx.x * 256 + threadIdx.x;
  if (i < n4) {
    float4 v = ((const float4*)in)[i];
    half4 h = { (_Float16)v.x, (_Float16)v.y, (_Float16)v.z, (_Float16)v.w };
    ((half4*)out)[i] = h;
  }
}

// ---------------- NT GEMM: C[M,N] = A[M,K] * B[N,K]^T ----------------
// 128x128 tile, BK=64, 256 threads (4 waves, 2x2 wave grid, 64x64 wave tile),
// mfma_f32_16x16x32_f16. LDS tiles XOR-swizzled (byte ^= (row&7)<<4) to kill
// the 16-way bank conflict of 128B row stride on ds_read_b128.
template<bool A_F32, bool EPI_Q>
__global__ __launch_bounds__(256, 2) void gemm_nt(const void* __restrict__ Ap,
                                                  const _Float16* __restrict__ Bh,
                                                  const float* __restrict__ bias,
                                                  void* __restrict__ outp,
                                                  int M, int N, int K, int nCol) {
  __shared__ __align__(16) _Float16 ldsA[128 * 64];
  __shared__ __align__(16) _Float16 ldsB[128 * 64];

  const int tid = threadIdx.x;
  const int rowBase = (blockIdx.x / nCol) * 128;
  const int colBase = (blockIdx.x % nCol) * 128;
  const int lane = tid & 63;
  const int wid  = tid >> 6;
  const int wr = (wid >> 1) * 64;
  const int wc = (wid & 1) * 64;
  const int l15 = lane & 15;
  const int q4  = lane >> 4;          // 0..3

  floatx4 acc[4][4];
  #pragma unroll
  for (int m = 0; m < 4; ++m)
    #pragma unroll
    for (int n = 0; n < 4; ++n)
      acc[m][n] = (floatx4)0.0f;

  for (int kt = 0; kt < K; kt += 64) {
    // ---- stage A (128 rows x 64 k); 16B slots, swizzled ----
    #pragma unroll
    for (int it = 0; it < 4; ++it) {
      int s = tid + it * 256;         // 0..1023
      int row = s >> 3, sl = s & 7;
      char* dst = (char*)ldsA + row * 128 + ((sl * 16) ^ ((row & 7) << 4));
      if (A_F32) {
        const float* src = (const float*)Ap + (size_t)(rowBase + row) * K + kt + sl * 8;
        float4 v0 = ((const float4*)src)[0];
        float4 v1 = ((const float4*)src)[1];
        half8 h = { (_Float16)v0.x, (_Float16)v0.y, (_Float16)v0.z, (_Float16)v0.w,
                    (_Float16)v1.x, (_Float16)v1.y, (_Float16)v1.z, (_Float16)v1.w };
        *(half8*)dst = h;
      } else {
        const _Float16* src = (const _Float16*)Ap + (size_t)(rowBase + row) * K + kt + sl * 8;
        *(uint4*)dst = *(const uint4*)src;
      }
    }
    // ---- stage B (always fp16 source) ----
    #pragma unroll
    for (int it = 0; it < 4; ++it) {
      int s = tid + it * 256;
      int row = s >> 3, sl = s & 7;
      char* dst = (char*)ldsB + row * 128 + ((sl * 16) ^ ((row & 7) << 4));
      const _Float16* src = Bh + (size_t)(colBase + row) * K + kt + sl * 8;
      *(uint4*)dst = *(const uint4*)src;
    }
    __syncthreads();

    #pragma unroll
    for (int ks = 0; ks < 2; ++ks) {     // two K=32 sub-steps
      const int slot = ks * 4 + q4;      // 16B slot index 0..7
      half8 a[4], b[4];
      #pragma unroll
      for (int m = 0; m < 4; ++m) {
        int row = wr + m * 16 + l15;
        a[m] = *(const half8*)((const char*)ldsA + row * 128 + ((slot * 16) ^ ((row & 7) << 4)));
      }
      #pragma unroll
      for (int n = 0; n < 4; ++n) {
        int row = wc + n * 16 + l15;
        b[n] = *(const half8*)((const char*)ldsB + row * 128 + ((slot * 16) ^ ((row & 7) << 4)));
      }
      #pragma unroll
      for (int m = 0; m < 4; ++m)
        #pragma unroll
        for (int n = 0; n < 4; ++n)
          acc[m][n] = __builtin_amdgcn_mfma_f32_16x16x32_f16(a[m], b[n], acc[m][n], 0, 0, 0);
    }
    __syncthreads();
  }

  // ---- epilogue: C/D layout col=lane&15, row=(lane>>4)*4+r ----
  #pragma unroll
  for (int m = 0; m < 4; ++m) {
    #pragma unroll
    for (int n = 0; n < 4; ++n) {
      int col = colBase + wc + n * 16 + l15;
      #pragma unroll
      for (int r = 0; r < 4; ++r) {
        int row = rowBase + wr + m * 16 + q4 * 4 + r;
        float v = acc[m][n][r];
        if (EPI_Q) {
          v += bias[col];
          ((_Float16*)outp)[(size_t)row * N + col] = (_Float16)v;
        } else {
          ((float*)outp)[(size_t)row * N + col] = v;
        }
      }
    }
  }
}

// ---------------- top-16 + scatter-softmax gates ----------------
// One block (256 thr) per row. Exact selection, jax tie-break (min index).
__global__ __launch_bounds__(256) void topk_gates_kernel(const float* __restrict__ scores,
                                                         float* __restrict__ gates) {
  __shared__ float wv[4][KTOP];
  __shared__ int   wi[4][KTOP];
  __shared__ float selv[KTOP];
  __shared__ int   seli[KTOP];
  __shared__ float gk[KTOP];
  __shared__ float s_gother;

  const int tid  = threadIdx.x;
  const int lane = tid & 63;
  const int w    = tid >> 6;
  const float* srow = scores + (size_t)blockIdx.x * NKEYS;

  // each wave owns 1024 contiguous elems; 16 per lane in registers
  float v[16];
  #pragma unroll
  for (int j = 0; j < 16; ++j) v[j] = srow[(w << 10) + (j << 6) + lane];

  // phase 1: per-wave top-16 via iterative argmax (value desc, index asc on ties)
  for (int k = 0; k < KTOP; ++k) {
    float bv = -__builtin_inff(); int bi = 0;
    #pragma unroll
    for (int j = 0; j < 16; ++j) {
      int gi = (w << 10) + (j << 6) + lane;
      if (v[j] > bv) { bv = v[j]; bi = gi; }
    }
    #pragma unroll
    for (int off = 32; off >= 1; off >>= 1) {
      float ov = __shfl_down(bv, off);
      int   oi = __shfl_down(bi, off);
      if (ov > bv || (ov == bv && oi < bi)) { bv = ov; bi = oi; }
    }
    int widx = __shfl(bi, 0);
    if (lane == 0) { wv[w][k] = bv; wi[w][k] = widx; }
    int jl = (widx >> 6) & 15;
    bool own = (widx & 63) == lane;
    #pragma unroll
    for (int j = 0; j < 16; ++j)
      if (own && j == jl) v[j] = -__builtin_inff();
  }
  __syncthreads();

  // phase 2: merge 4x16 candidates on wave 0
  if (w == 0) {
    float cv = wv[lane >> 4][lane & 15];
    int   ci = wi[lane >> 4][lane & 15];
    for (int k = 0; k < KTOP; ++k) {
      float bv = cv; int bi = ci;
      #pragma unroll
      for (int off = 32; off >= 1; off >>= 1) {
        float ov = __shfl_down(bv, off);
        int   oi = __shfl_down(bi, off);
        if (ov > bv || (ov == bv && oi < bi)) { bv = ov; bi = oi; }
      }
      bi = __shfl(bi, 0); bv = __shfl(bv, 0);
      if (lane == 0) { selv[k] = bv; seli[k] = bi; }
      if (ci == bi) cv = -__builtin_inff();
    }
  }
  __syncthreads();

  // softmax over scattered row: m = max(top1, 0); Z includes the 4080 zeros
  if (tid == 0) {
    float m = selv[0] > 0.f ? selv[0] : 0.f;
    float eo = __expf(-m);
    float Z = (float)(NKEYS - KTOP) * eo;
    float e[KTOP];
    #pragma unroll
    for (int k = 0; k < KTOP; ++k) { e[k] = __expf(selv[k] - m); Z += e[k]; }
    float inv = 1.f / Z;
    #pragma unroll
    for (int k = 0; k < KTOP; ++k) gk[k] = e[k] * inv;
    s_gother = eo * inv;
  }
  __syncthreads();

  // bulk fill, then scatter the 16 top gates
  float go = s_gother;
  float4 g4 = { go, go, go, go };
  float* grow = gates + (size_t)blockIdx.x * NKEYS;
  #pragma unroll
  for (int j = 0; j < 4; ++j) ((float4*)grow)[j * 256 + tid] = g4;
  __syncthreads();   // drain bulk stores before overwriting top positions
  if (tid < KTOP) grow[seli[tid]] = gk[tid];
}

extern "C" void kernel_launch(void* const* d_in, const int* in_sizes, int n_in,
                              void* d_out, int out_size, void* d_ws, size_t ws_size,
                              hipStream_t stream) {
  const float* x    = (const float*)d_in[0];
  const float* keys = (const float*)d_in[1];
  const float* W    = (const float*)d_in[2];
  const float* bias = (const float*)d_in[3];
  (void)in_sizes; (void)n_in; (void)out_size; (void)ws_size;  // topk fixed at 16

  float* gates  = (float*)d_out;
  float* scores = (float*)d_out + (size_t)BS_T * NKEYS;

  _Float16* W_h = (_Float16*)d_ws;                 // 4 MB
  _Float16* k_h = W_h + (size_t)KDIM * XDIM;       // 4 MB
  _Float16* q_h = k_h + (size_t)NKEYS * KDIM;      // 16 MB

  cvt_f32_f16<<<dim3((KDIM * XDIM / 4) / 256), dim3(256), 0, stream>>>(W, W_h, KDIM * XDIM / 4);
  cvt_f32_f16<<<dim3((NKEYS * KDIM / 4) / 256), dim3(256), 0, stream>>>(keys, k_h, NKEYS * KDIM / 4);

  // query = x @ W^T + b  -> q_h (fp16)
  gemm_nt<true, true><<<dim3((BS_T / 128) * (KDIM / 128)), dim3(256), 0, stream>>>(
      x, W_h, bias, q_h, BS_T, KDIM, XDIM, KDIM / 128);

  // scores = q @ keys^T -> d_out second half (fp32)
  gemm_nt<false, false><<<dim3((BS_T / 128) * (NKEYS / 128)), dim3(256), 0, stream>>>(
      q_h, k_h, nullptr, scores, BS_T, NKEYS, KDIM, NKEYS / 128);

  topk_gates_kernel<<<dim3(BS_T), dim3(256), 0, stream>>>(scores, gates);
}

// Round 2
// 596.650 us; speedup vs baseline: 1.1975x; 1.1975x over previous
//
#include <hip/hip_runtime.h>
#include <stdint.h>

#define BS_T   16384
#define XDIM   4096
#define KDIM   512
#define NKEYS  4096
#define KTOP   16

typedef _Float16 half8  __attribute__((ext_vector_type(8)));
typedef _Float16 half4  __attribute__((ext_vector_type(4)));
typedef float    floatx4 __attribute__((ext_vector_type(4)));

// async global->LDS, 16B per lane; LDS dest is wave-uniform base + lane*16
__device__ static inline void gload_lds16(const void* g, void* l) {
  __builtin_amdgcn_global_load_lds(
      (const __attribute__((address_space(1))) uint32_t*)(uintptr_t)g,
      (__attribute__((address_space(3))) uint32_t*)(uint32_t)(uintptr_t)l,
      16, 0, 0);
}

// ---------------- fp32 -> fp16 convert (vectorized, grid-stride) ----------------
__global__ __launch_bounds__(256) void cvt_f32_f16_v(const float* __restrict__ in,
                                                     _Float16* __restrict__ out, int n8) {
  int stride = gridDim.x * 256;
  for (int i = blockIdx.x * 256 + threadIdx.x; i < n8; i += stride) {
    float4 v0 = ((const float4*)in)[2 * i];
    float4 v1 = ((const float4*)in)[2 * i + 1];
    half8 h = { (_Float16)v0.x, (_Float16)v0.y, (_Float16)v0.z, (_Float16)v0.w,
                (_Float16)v1.x, (_Float16)v1.y, (_Float16)v1.z, (_Float16)v1.w };
    ((half8*)out)[i] = h;
  }
}

// ---------------- NT GEMM: C[M,N] = A[M,K] * B[N,K]^T, fp16 in, BK=64 ----------------
// global_load_lds width-16 staging, linear LDS dest + inverse-swizzled global source,
// XOR-swizzled ds_read_b128 (conflict-free, verified 0 conflicts in R0).
template<int BM, int BN, int WTM, int WTN, int MINW, bool EPI_Q>
__global__ __launch_bounds__(256, MINW)
void gemm16(const _Float16* __restrict__ A, const _Float16* __restrict__ B,
            const float* __restrict__ bias, void* __restrict__ outp,
            int M, int N, int K, int nCol) {
  __shared__ __align__(16) _Float16 ldsA[BM * 64];
  __shared__ __align__(16) _Float16 ldsB[BN * 64];

  const int tid = threadIdx.x;
  // XCD-chunked bijective swizzle (nwg % 8 == 0 for all our grids)
  const int cpx = gridDim.x >> 3;
  const int bid = (blockIdx.x & 7) * cpx + (blockIdx.x >> 3);
  const int rowBase = (bid / nCol) * BM;
  const int colBase = (bid % nCol) * BN;
  const int lane = tid & 63;
  const int wid  = tid >> 6;
  const int wr = (wid >> 1) * (WTM * 16);
  const int wc = (wid & 1) * (WTN * 16);
  const int l15 = lane & 15;
  const int q4  = lane >> 4;

  // staging geometry: one wave-instr covers 8 rows x 128B; lane -> (row sub, slot)
  const int sub   = lane >> 3;          // row within the 8-row group
  const int gslot = (lane & 7) ^ sub;   // pre-swizzled global 16B slot (row&7 == sub)

  floatx4 acc[WTM][WTN];
  #pragma unroll
  for (int m = 0; m < WTM; ++m)
    #pragma unroll
    for (int n = 0; n < WTN; ++n)
      acc[m][n] = (floatx4)0.0f;

  for (int kt = 0; kt < K; kt += 64) {
    #pragma unroll
    for (int i = 0; i < BM / 32; ++i) {
      int t = wid * (BM / 32) + i;
      const _Float16* src = A + (size_t)(rowBase + t * 8 + sub) * K + kt + gslot * 8;
      gload_lds16(src, (char*)ldsA + t * 1024);
    }
    #pragma unroll
    for (int i = 0; i < BN / 32; ++i) {
      int t = wid * (BN / 32) + i;
      const _Float16* src = B + (size_t)(colBase + t * 8 + sub) * K + kt + gslot * 8;
      gload_lds16(src, (char*)ldsB + t * 1024);
    }
    __syncthreads();

    #pragma unroll
    for (int ks = 0; ks < 2; ++ks) {
      const int s = ks * 4 + q4;        // 16B slot 0..7 within the 128B row
      half8 a[WTM], b[WTN];
      #pragma unroll
      for (int m = 0; m < WTM; ++m) {
        int row = wr + m * 16 + l15;
        a[m] = *(const half8*)((const char*)ldsA + row * 128 + ((s * 16) ^ ((row & 7) << 4)));
      }
      #pragma unroll
      for (int n = 0; n < WTN; ++n) {
        int row = wc + n * 16 + l15;
        b[n] = *(const half8*)((const char*)ldsB + row * 128 + ((s * 16) ^ ((row & 7) << 4)));
      }
      #pragma unroll
      for (int m = 0; m < WTM; ++m)
        #pragma unroll
        for (int n = 0; n < WTN; ++n)
          acc[m][n] = __builtin_amdgcn_mfma_f32_16x16x32_f16(a[m], b[n], acc[m][n], 0, 0, 0);
    }
    __syncthreads();
  }

  // epilogue: C/D layout col=lane&15, row=(lane>>4)*4+r
  #pragma unroll
  for (int m = 0; m < WTM; ++m) {
    #pragma unroll
    for (int n = 0; n < WTN; ++n) {
      int col = colBase + wc + n * 16 + l15;
      #pragma unroll
      for (int r = 0; r < 4; ++r) {
        int row = rowBase + wr + m * 16 + q4 * 4 + r;
        float v = acc[m][n][r];
        if (EPI_Q) {
          v += bias[col];
          ((_Float16*)outp)[(size_t)row * N + col] = (_Float16)v;
        } else {
          ((float*)outp)[(size_t)row * N + col] = v;
        }
      }
    }
  }
}

// ---------------- top-16 + scatter-softmax gates ----------------
// One block (256 thr) per row. Exact selection, jax tie-break (min index).
__global__ __launch_bounds__(256) void topk_gates_kernel(const float* __restrict__ scores,
                                                         float* __restrict__ gates) {
  __shared__ float wv[4][KTOP];
  __shared__ int   wi[4][KTOP];
  __shared__ float selv[KTOP];
  __shared__ int   seli[KTOP];
  __shared__ float gk[KTOP];
  __shared__ float s_gother;

  const int tid  = threadIdx.x;
  const int lane = tid & 63;
  const int w    = tid >> 6;
  const float* srow = scores + (size_t)blockIdx.x * NKEYS;

  // each wave owns 1024 contiguous elems; lane owns 16 contiguous (4x float4)
  float v[16];
  {
    const float4* p = (const float4*)(srow + (w << 10) + (lane << 4));
    #pragma unroll
    for (int i = 0; i < 4; ++i) {
      float4 t = p[i];
      v[i * 4 + 0] = t.x; v[i * 4 + 1] = t.y; v[i * 4 + 2] = t.z; v[i * 4 + 3] = t.w;
    }
  }

  // phase 1: per-wave top-16 via iterative argmax (value desc, index asc on ties)
  for (int k = 0; k < KTOP; ++k) {
    float bv = -__builtin_inff(); int bi = 0;
    #pragma unroll
    for (int j = 0; j < 16; ++j) {
      int gi = (w << 10) + (lane << 4) + j;
      if (v[j] > bv) { bv = v[j]; bi = gi; }
    }
    #pragma unroll
    for (int off = 32; off >= 1; off >>= 1) {
      float ov = __shfl_down(bv, off);
      int   oi = __shfl_down(bi, off);
      if (ov > bv || (ov == bv && oi < bi)) { bv = ov; bi = oi; }
    }
    int widx = __shfl(bi, 0);
    if (lane == 0) { wv[w][k] = bv; wi[w][k] = widx; }
    int jl = widx & 15;
    bool own = ((widx >> 4) & 63) == lane;
    #pragma unroll
    for (int j = 0; j < 16; ++j)
      if (own && j == jl) v[j] = -__builtin_inff();
  }
  __syncthreads();

  // phase 2: merge 4x16 candidates on wave 0
  if (w == 0) {
    float cv = wv[lane >> 4][lane & 15];
    int   ci = wi[lane >> 4][lane & 15];
    for (int k = 0; k < KTOP; ++k) {
      float bv = cv; int bi = ci;
      #pragma unroll
      for (int off = 32; off >= 1; off >>= 1) {
        float ov = __shfl_down(bv, off);
        int   oi = __shfl_down(bi, off);
        if (ov > bv || (ov == bv && oi < bi)) { bv = ov; bi = oi; }
      }
      bi = __shfl(bi, 0); bv = __shfl(bv, 0);
      if (lane == 0) { selv[k] = bv; seli[k] = bi; }
      if (ci == bi) cv = -__builtin_inff();
    }
  }
  __syncthreads();

  // softmax over scattered row: m = max(top1, 0); Z includes the 4080 zeros
  if (tid == 0) {
    float m = selv[0] > 0.f ? selv[0] : 0.f;
    float eo = __expf(-m);
    float Z = (float)(NKEYS - KTOP) * eo;
    float e[KTOP];
    #pragma unroll
    for (int k = 0; k < KTOP; ++k) { e[k] = __expf(selv[k] - m); Z += e[k]; }
    float inv = 1.f / Z;
    #pragma unroll
    for (int k = 0; k < KTOP; ++k) gk[k] = e[k] * inv;
    s_gother = eo * inv;
  }
  __syncthreads();

  // bulk fill, then scatter the 16 top gates
  float go = s_gother;
  float4 g4 = { go, go, go, go };
  float* grow = gates + (size_t)blockIdx.x * NKEYS;
  #pragma unroll
  for (int j = 0; j < 4; ++j) ((float4*)grow)[j * 256 + tid] = g4;
  __syncthreads();   // drain bulk stores before overwriting top positions
  if (tid < KTOP) grow[seli[tid]] = gk[tid];
}

extern "C" void kernel_launch(void* const* d_in, const int* in_sizes, int n_in,
                              void* d_out, int out_size, void* d_ws, size_t ws_size,
                              hipStream_t stream) {
  const float* x    = (const float*)d_in[0];
  const float* keys = (const float*)d_in[1];
  const float* W    = (const float*)d_in[2];
  const float* bias = (const float*)d_in[3];
  (void)in_sizes; (void)n_in; (void)out_size; (void)ws_size;

  float* gates  = (float*)d_out;
  float* scores = (float*)d_out + (size_t)BS_T * NKEYS;

  _Float16* W_h = (_Float16*)d_ws;                 // 4 MB
  _Float16* k_h = W_h + (size_t)KDIM * XDIM;       // 4 MB
  _Float16* q_h = k_h + (size_t)NKEYS * KDIM;      // 16 MB
  // x_h (128 MB, fp16) lives in the gates half of d_out; topk rewrites gates at the end
  _Float16* x_h = (_Float16*)gates;

  cvt_f32_f16_v<<<dim3(4096), dim3(256), 0, stream>>>(x, x_h, BS_T * XDIM / 8);
  cvt_f32_f16_v<<<dim3(1024), dim3(256), 0, stream>>>(W, W_h, KDIM * XDIM / 8);
  cvt_f32_f16_v<<<dim3(1024), dim3(256), 0, stream>>>(keys, k_h, NKEYS * KDIM / 8);

  // query = x @ W^T + b -> q_h (fp16). 128x64 tiles, grid 1024 (4 blocks/CU)
  gemm16<128, 64, 4, 2, 4, true><<<dim3((BS_T / 128) * (KDIM / 64)), dim3(256), 0, stream>>>(
      x_h, W_h, bias, q_h, BS_T, KDIM, XDIM, KDIM / 64);

  // scores = q @ keys^T -> fp32. 128x128 tiles, grid 4096
  gemm16<128, 128, 4, 4, 3, false><<<dim3((BS_T / 128) * (NKEYS / 128)), dim3(256), 0, stream>>>(
      q_h, k_h, nullptr, scores, BS_T, NKEYS, KDIM, NKEYS / 128);

  topk_gates_kernel<<<dim3(BS_T), dim3(256), 0, stream>>>(scores, gates);
}

// Round 3
// 444.908 us; speedup vs baseline: 1.6059x; 1.3411x over previous
//
#include <hip/hip_runtime.h>
#include <stdint.h>

#define BS_T   16384
#define XDIM   4096
#define KDIM   512
#define NKEYS  4096
#define KTOP   16

typedef _Float16 half8  __attribute__((ext_vector_type(8)));
typedef float    floatx4 __attribute__((ext_vector_type(4)));

// async global->LDS, 16B per lane; LDS dest is wave-uniform base + lane*16
__device__ static inline void gload_lds16(const void* g, void* l) {
  __builtin_amdgcn_global_load_lds(
      (const __attribute__((address_space(1))) uint32_t*)(uintptr_t)g,
      (__attribute__((address_space(3))) uint32_t*)(uint32_t)(uintptr_t)l,
      16, 0, 0);
}

// ---------------- fp32 -> fp16 convert (vectorized, grid-stride) ----------------
__global__ __launch_bounds__(256) void cvt_f32_f16_v(const float* __restrict__ in,
                                                     _Float16* __restrict__ out, int n8) {
  int stride = gridDim.x * 256;
  for (int i = blockIdx.x * 256 + threadIdx.x; i < n8; i += stride) {
    float4 v0 = ((const float4*)in)[2 * i];
    float4 v1 = ((const float4*)in)[2 * i + 1];
    half8 h = { (_Float16)v0.x, (_Float16)v0.y, (_Float16)v0.z, (_Float16)v0.w,
                (_Float16)v1.x, (_Float16)v1.y, (_Float16)v1.z, (_Float16)v1.w };
    ((half8*)out)[i] = h;
  }
}

// ---------------- NT GEMM: C[M,N] = A[M,K] * B[N,K]^T, fp16 in, BK=64 ----------------
template<int BM, int BN, int WTM, int WTN, int MINW, bool EPI_Q>
__global__ __launch_bounds__(256, MINW)
void gemm16(const _Float16* __restrict__ A, const _Float16* __restrict__ B,
            const float* __restrict__ bias, void* __restrict__ outp,
            int M, int N, int K, int nCol) {
  __shared__ __align__(16) _Float16 ldsA[BM * 64];
  __shared__ __align__(16) _Float16 ldsB[BN * 64];

  const int tid = threadIdx.x;
  const int cpx = gridDim.x >> 3;
  const int bid = (blockIdx.x & 7) * cpx + (blockIdx.x >> 3);
  const int rowBase = (bid / nCol) * BM;
  const int colBase = (bid % nCol) * BN;
  const int lane = tid & 63;
  const int wid  = tid >> 6;
  const int wr = (wid >> 1) * (WTM * 16);
  const int wc = (wid & 1) * (WTN * 16);
  const int l15 = lane & 15;
  const int q4  = lane >> 4;

  const int sub   = lane >> 3;          // row within the 8-row group
  const int gslot = (lane & 7) ^ sub;   // pre-swizzled global 16B slot

  floatx4 acc[WTM][WTN];
  #pragma unroll
  for (int m = 0; m < WTM; ++m)
    #pragma unroll
    for (int n = 0; n < WTN; ++n)
      acc[m][n] = (floatx4)0.0f;

  for (int kt = 0; kt < K; kt += 64) {
    #pragma unroll
    for (int i = 0; i < BM / 32; ++i) {
      int t = wid * (BM / 32) + i;
      const _Float16* src = A + (size_t)(rowBase + t * 8 + sub) * K + kt + gslot * 8;
      gload_lds16(src, (char*)ldsA + t * 1024);
    }
    #pragma unroll
    for (int i = 0; i < BN / 32; ++i) {
      int t = wid * (BN / 32) + i;
      const _Float16* src = B + (size_t)(colBase + t * 8 + sub) * K + kt + gslot * 8;
      gload_lds16(src, (char*)ldsB + t * 1024);
    }
    __syncthreads();

    #pragma unroll
    for (int ks = 0; ks < 2; ++ks) {
      const int s = ks * 4 + q4;
      half8 a[WTM], b[WTN];
      #pragma unroll
      for (int m = 0; m < WTM; ++m) {
        int row = wr + m * 16 + l15;
        a[m] = *(const half8*)((const char*)ldsA + row * 128 + ((s * 16) ^ ((row & 7) << 4)));
      }
      #pragma unroll
      for (int n = 0; n < WTN; ++n) {
        int row = wc + n * 16 + l15;
        b[n] = *(const half8*)((const char*)ldsB + row * 128 + ((s * 16) ^ ((row & 7) << 4)));
      }
      #pragma unroll
      for (int m = 0; m < WTM; ++m)
        #pragma unroll
        for (int n = 0; n < WTN; ++n)
          acc[m][n] = __builtin_amdgcn_mfma_f32_16x16x32_f16(a[m], b[n], acc[m][n], 0, 0, 0);
    }
    __syncthreads();
  }

  #pragma unroll
  for (int m = 0; m < WTM; ++m) {
    #pragma unroll
    for (int n = 0; n < WTN; ++n) {
      int col = colBase + wc + n * 16 + l15;
      #pragma unroll
      for (int r = 0; r < 4; ++r) {
        int row = rowBase + wr + m * 16 + q4 * 4 + r;
        float v = acc[m][n][r];
        if (EPI_Q) {
          v += bias[col];
          ((_Float16*)outp)[(size_t)row * N + col] = (_Float16)v;
        } else {
          ((float*)outp)[(size_t)row * N + col] = v;
        }
      }
    }
  }
}

// ---------------- top-16 + scatter-softmax gates (radix-select) ----------------
// One block (256 thr) per row. Exact selection, jax tie-break (value desc, min idx).
// Order-preserving key transform -> 12-bit-bin histogram -> pivot bin of the 16th
// largest -> bins above pivot selected wholesale, boundary filled from pivot-bin
// candidates (typically ~1-4 rounds over ~10 candidates).
__global__ __launch_bounds__(256) void topk_gates_kernel(const float* __restrict__ scores,
                                                         float* __restrict__ gates) {
  __shared__ uint32_t hist[4096];            // 16KB; reused as candidate store
  __shared__ uint32_t sA[256];               // group-suffix scan buffer
  __shared__ uint32_t av[16], ai[16];        // strictly-above-pivot-bin elems (<=15)
  __shared__ uint32_t sk[KTOP], si[KTOP];    // selected keys / indices
  __shared__ uint32_t cntA, cntC;
  __shared__ int s_p; __shared__ uint32_t s_above;
  __shared__ float gk[KTOP]; __shared__ float s_gother;

  const int tid  = threadIdx.x;
  const int lane = tid & 63;
  const int w    = tid >> 6;
  const float* srow = scores + (size_t)blockIdx.x * NKEYS;

  // zero hist + counters
  uint4 z4 = {0, 0, 0, 0};
  #pragma unroll
  for (int i = 0; i < 4; ++i) ((uint4*)hist)[tid + 256 * i] = z4;
  if (tid == 0) { cntA = 0; cntC = 0; }

  // load 16 contiguous scores per lane; monotonic uint key transform
  uint32_t key[16];
  const int base = (w << 10) + (lane << 4);
  {
    const float4* p4 = (const float4*)(srow + base);
    #pragma unroll
    for (int i = 0; i < 4; ++i) {
      float4 t = p4[i];
      float tv[4] = { t.x, t.y, t.z, t.w };
      #pragma unroll
      for (int c = 0; c < 4; ++c) {
        uint32_t u = __float_as_uint(tv[c]);
        key[i * 4 + c] = u ^ (uint32_t)(((int32_t)u >> 31) | 0x80000000);
      }
    }
  }
  __syncthreads();

  #pragma unroll
  for (int j = 0; j < 16; ++j) atomicAdd(&hist[key[j] >> 20], 1u);
  __syncthreads();

  // per-thread suffix over its 16 bins, then inclusive suffix scan of group sums
  uint32_t h[16];
  #pragma unroll
  for (int i = 0; i < 16; ++i) h[i] = hist[tid * 16 + i];
  uint32_t sfx[17]; sfx[16] = 0;
  #pragma unroll
  for (int i = 15; i >= 0; --i) sfx[i] = sfx[i + 1] + h[i];
  sA[tid] = sfx[0];
  __syncthreads();
  uint32_t s = sfx[0];
  #pragma unroll
  for (int off = 1; off < 256; off <<= 1) {
    uint32_t add = (tid + off < 256) ? sA[tid + off] : 0;
    __syncthreads();
    s += add; sA[tid] = s;
    __syncthreads();
  }
  const uint32_t exclHi = s - sfx[0];        // elems in groups strictly above

  // pivot bin: cnt_gt < 16 <= cnt_gt + hist[bin]  (exactly one bin matches)
  #pragma unroll
  for (int i = 0; i < 16; ++i) {
    uint32_t cg = exclHi + sfx[i + 1];
    if (cg < KTOP && cg + h[i] >= KTOP) { s_p = tid * 16 + i; s_above = cg; }
  }
  __syncthreads();
  const uint32_t p = (uint32_t)s_p;
  const uint32_t above = s_above;
  const uint32_t need = KTOP - above;

  // collect: above-bins wholesale, pivot-bin into candidate store (reuse hist LDS)
  uint32_t* ck = hist;            // [2048] keys
  uint32_t* ci = hist + 2048;     // [2048] indices
  #pragma unroll
  for (int j = 0; j < 16; ++j) {
    uint32_t b = key[j] >> 20;
    if (b >= p) {
      uint32_t idx = (uint32_t)(base + j);
      if (b > p) { uint32_t pos = atomicAdd(&cntA, 1u); av[pos] = key[j]; ai[pos] = idx; }
      else       { uint32_t pos = atomicAdd(&cntC, 1u); if (pos < 2048u) { ck[pos] = key[j]; ci[pos] = idx; } }
    }
  }
  __syncthreads();

  const uint32_t nA = cntA;
  if (tid < nA) { sk[tid] = av[tid]; si[tid] = ai[tid]; }

  // boundary selection on wave 0: `need` rounds of (key desc, idx asc) argmax
  if (w == 0) {
    const uint32_t nC = min(cntC, 2048u);
    for (uint32_t k = 0; k < need; ++k) {
      uint32_t bk = 0, bi = 0xFFFFFFFFu, bp = 0;
      for (uint32_t c = lane; c < nC; c += 64) {
        uint32_t kk = ck[c], ii = ci[c];
        if (kk > bk || (kk == bk && ii < bi)) { bk = kk; bi = ii; bp = c; }
      }
      #pragma unroll
      for (int off = 32; off >= 1; off >>= 1) {
        uint32_t ok = __shfl_down(bk, off);
        uint32_t oi = __shfl_down(bi, off);
        uint32_t op = __shfl_down(bp, off);
        if (ok > bk || (ok == bk && oi < bi)) { bk = ok; bi = oi; bp = op; }
      }
      bp = __shfl(bp, 0);
      if (lane == 0) { ck[bp] = 0; sk[nA + k] = bk; si[nA + k] = bi; }
    }
  }
  __syncthreads();

  // softmax over scattered row: m = max(top1, 0); Z includes the 4080 zeros
  if (tid == 0) {
    float f[KTOP]; float mx = 0.f;
    #pragma unroll
    for (int k = 0; k < KTOP; ++k) {
      uint32_t kk = sk[k];
      float fv = (kk & 0x80000000u) ? __uint_as_float(kk ^ 0x80000000u)
                                    : __uint_as_float(~kk);
      f[k] = fv; mx = fmaxf(mx, fv);
    }
    float eo = __expf(-mx);
    float Z = (float)(NKEYS - KTOP) * eo;
    float e[KTOP];
    #pragma unroll
    for (int k = 0; k < KTOP; ++k) { e[k] = __expf(f[k] - mx); Z += e[k]; }
    float inv = 1.f / Z;
    #pragma unroll
    for (int k = 0; k < KTOP; ++k) gk[k] = e[k] * inv;
    s_gother = eo * inv;
  }
  __syncthreads();

  // bulk fill, then scatter the 16 top gates
  float go = s_gother;
  float4 g4 = { go, go, go, go };
  float* grow = gates + (size_t)blockIdx.x * NKEYS;
  #pragma unroll
  for (int j = 0; j < 4; ++j) ((float4*)grow)[j * 256 + tid] = g4;
  __syncthreads();
  if (tid < KTOP) grow[si[tid]] = gk[tid];
}

extern "C" void kernel_launch(void* const* d_in, const int* in_sizes, int n_in,
                              void* d_out, int out_size, void* d_ws, size_t ws_size,
                              hipStream_t stream) {
  const float* x    = (const float*)d_in[0];
  const float* keys = (const float*)d_in[1];
  const float* W    = (const float*)d_in[2];
  const float* bias = (const float*)d_in[3];
  (void)in_sizes; (void)n_in; (void)out_size; (void)ws_size;

  float* gates  = (float*)d_out;
  float* scores = (float*)d_out + (size_t)BS_T * NKEYS;

  _Float16* W_h = (_Float16*)d_ws;                 // 4 MB
  _Float16* k_h = W_h + (size_t)KDIM * XDIM;       // 4 MB
  _Float16* q_h = k_h + (size_t)NKEYS * KDIM;      // 16 MB
  // x_h (128 MB fp16) lives in the gates half of d_out; topk rewrites gates last
  _Float16* x_h = (_Float16*)gates;

  cvt_f32_f16_v<<<dim3(4096), dim3(256), 0, stream>>>(x, x_h, BS_T * XDIM / 8);
  cvt_f32_f16_v<<<dim3(1024), dim3(256), 0, stream>>>(W, W_h, KDIM * XDIM / 8);
  cvt_f32_f16_v<<<dim3(1024), dim3(256), 0, stream>>>(keys, k_h, NKEYS * KDIM / 8);

  // query = x @ W^T + b -> q_h (fp16). 128x64 tiles, grid 1024
  gemm16<128, 64, 4, 2, 4, true><<<dim3((BS_T / 128) * (KDIM / 64)), dim3(256), 0, stream>>>(
      x_h, W_h, bias, q_h, BS_T, KDIM, XDIM, KDIM / 64);

  // scores = q @ keys^T -> fp32. 128x128 tiles, grid 4096
  gemm16<128, 128, 4, 4, 3, false><<<dim3((BS_T / 128) * (NKEYS / 128)), dim3(256), 0, stream>>>(
      q_h, k_h, nullptr, scores, BS_T, NKEYS, KDIM, NKEYS / 128);

  topk_gates_kernel<<<dim3(BS_T), dim3(256), 0, stream>>>(scores, gates);
}